// Round 8
// baseline (270.061 us; speedup 1.0000x reference)
//
#include <hip/hip_runtime.h>

// MHA forward: out = softmax(mask(QK^T/8)) V, with QKV/out projections.
// B=4, S=2048, D=1024, H=16, hd=64. fp32 in/out, bf16 MFMA compute.
// Mask [B,1,1,S] -> compact K/V to unmasked keys (~50%). Softmax scale
// folded into K projection. Attention reads K/V straight from L2 (no LDS).

#define SEQ   2048
#define EDIM  1024
#define NHEAD 16
#define HDIM  64
#define NBAT  4
#define MTOK  8192           // B*S

typedef __attribute__((ext_vector_type(8))) __bf16 bf16x8;
typedef __attribute__((ext_vector_type(4))) __bf16 bf16x4;
typedef __attribute__((ext_vector_type(4))) float f32x4;
typedef __attribute__((ext_vector_type(16))) float f32x16;
typedef __attribute__((ext_vector_type(8))) unsigned short us8;
typedef unsigned short u16;

// log2(e)/8 : folds the 1/sqrt(hd) scale and the exp->exp2 conversion
#define SCL   0.1803368801111244f

__device__ __forceinline__ u16 bfbits(float f) {
    __bf16 h = (__bf16)f;
    return __builtin_bit_cast(u16, h);
}
__device__ __forceinline__ bf16x8 bc(us8 v) { return __builtin_bit_cast(bf16x8, v); }
__device__ __forceinline__ float exp2fast(float x) {
    float r;
    asm("v_exp_f32 %0, %1" : "=v"(r) : "v"(x));
    return r;
}
// async global->LDS, 16B per lane; LDS dest = wave-uniform base + lane*16
__device__ __forceinline__ void glds16(const void* g, void* l) {
    __builtin_amdgcn_global_load_lds(
        (const __attribute__((address_space(1))) unsigned int*)g,
        (__attribute__((address_space(3))) unsigned int*)l, 16, 0, 0);
}
#define VMCNT(n) asm volatile("s_waitcnt vmcnt(" #n ")" ::: "memory")

// ---------------------------------------------------------------------------
// Kernel 0: per-batch compaction of the key mask.
// ---------------------------------------------------------------------------
__global__ __launch_bounds__(256) void prep_kernel(const int* __restrict__ mask,
                                                   int* __restrict__ idxl,
                                                   int* __restrict__ cntp) {
    __shared__ int psum[257];
    const int b = blockIdx.x, t = threadIdx.x;
    const int* mp = mask + b * SEQ;
    int m8[8]; int s = 0;
#pragma unroll
    for (int i = 0; i < 8; ++i) { m8[i] = mp[t * 8 + i]; s += (m8[i] != 0); }
    psum[t + 1] = s;
    __syncthreads();
    if (t == 0) { psum[0] = 0; for (int i = 1; i <= 256; ++i) psum[i] += psum[i - 1]; }
    __syncthreads();
    int ex = psum[t];
#pragma unroll
    for (int i = 0; i < 8; ++i)
        if (m8[i] != 0) idxl[b * SEQ + (ex++)] = t * 8 + i;
    if (t == 0) cntp[b] = psum[256];
}

// ---------------------------------------------------------------------------
// Kernel 1: 4x W [K,N] fp32 -> WT [N,K] bf16 (transpose + cast)
// ---------------------------------------------------------------------------
__global__ __launch_bounds__(256) void wtrans4_kernel(const float* __restrict__ W0,
                                                      const float* __restrict__ W1,
                                                      const float* __restrict__ W2,
                                                      const float* __restrict__ W3,
                                                      u16* __restrict__ WT) {
    __shared__ float tile[32][33];
    const int tx = threadIdx.x, ty = threadIdx.y;
    const int bx = blockIdx.x,  by = blockIdx.y, wz = blockIdx.z;
    const float* W = (wz == 0) ? W0 : (wz == 1) ? W1 : (wz == 2) ? W2 : W3;
    u16* O = WT + (size_t)wz * EDIM * EDIM;
#pragma unroll
    for (int i = 0; i < 4; ++i)
        tile[ty + i * 8][tx] = W[(size_t)(by * 32 + ty + i * 8) * EDIM + bx * 32 + tx];
    __syncthreads();
#pragma unroll
    for (int i = 0; i < 4; ++i) {
        int n = bx * 32 + ty + i * 8;
        int k = by * 32 + tx;
        O[(size_t)n * EDIM + k] = bfbits(tile[tx][ty + i * 8]);
    }
}

// ---------------------------------------------------------------------------
// Kernel 2: C[M=8192, N=1024] = (A[M,1024] * W[1024,N] + bias) * oscale
//   MODE 0: bf16 [B,H,S,64] (Q,K); MODE 1: bf16 [B,H,64,S] (V^T);
//   MODE 2: fp32 [M,N] (final). GATHER: A rows via idxl, tail rows -> 0.
// glds16 staging, triple-buffered, counted vmcnt, 1 barrier per K-step.
// 1D grid, XCD-resident A-panel swizzle: XCD x owns bm === x (mod 8);
// order per XCD: {4 A-panels} x {all bn} -> working set ~2.5MB < 4MB L2.
// ---------------------------------------------------------------------------
template <int MODE, bool AFP32, bool GATHER>
__global__ __launch_bounds__(256) void gemm_kernel(const void* __restrict__ Ap,
                                                   const u16* __restrict__ WT,
                                                   const float* __restrict__ bias,
                                                   void* __restrict__ outp,
                                                   const int* __restrict__ idxl,
                                                   const int* __restrict__ cntp,
                                                   const float oscale) {
    const int id  = blockIdx.x;                 // 0..511
    const int r_  = id >> 3;
    const int grp = r_ >> 5, bnq = (r_ >> 2) & 7, bmin = r_ & 3;
    const int bm  = (id & 7) + 8 * (grp * 4 + bmin);
    const int bn  = bnq;

    int cn = 0;
    if constexpr (GATHER) {
        cn = cntp[bm >> 4];
        if (((bm & 15) * 128) >= cn) return;
    }

    constexpr int ASZ = 128 * 32 * (AFP32 ? 4 : 2);
    __shared__ __align__(16) char Asraw[3][ASZ];
    __shared__ __align__(16) u16 Bs[3][128][32];

    const int tid  = threadIdx.x;
    const int lane = tid & 63, w = tid >> 6;
    const int g    = lane >> 4, l15 = lane & 15;
    const int wrow = w >> 1, wcol = w & 1;

    const char* pa[4];
    if constexpr (AFP32) {
        const float* A = (const float*)Ap;
#pragma unroll
        for (int t = 0; t < 4; ++t) {
            const int rloc = w * 32 + t * 8 + (lane >> 3);
            int arow;
            if constexpr (GATHER) {
                const int sloc = (bm & 15) * 128 + rloc;
                const int gi = (sloc < cn) ? idxl[(bm >> 4) * SEQ + sloc] : 0;
                arow = (bm >> 4) * SEQ + gi;
            } else arow = bm * 128 + rloc;
            const int scol = ((lane & 7) ^ (lane >> 3)) * 4;
            pa[t] = (const char*)(A + (size_t)arow * EDIM + scol);
        }
    } else {
        const u16* A = (const u16*)Ap;
#pragma unroll
        for (int t = 0; t < 2; ++t) {
            const int rloc = w * 32 + t * 16 + (lane >> 2);
            const int arow = bm * 128 + rloc;
            const int scol = ((lane & 3) ^ ((lane >> 3) & 3)) * 8;
            pa[t] = (const char*)(A + (size_t)arow * EDIM + scol);
        }
    }
    const char* pb[2];
#pragma unroll
    for (int t = 0; t < 2; ++t) {
        const int rloc = w * 32 + t * 16 + (lane >> 2);
        const int brow = bn * 128 + rloc;
        const int scol = ((lane & 3) ^ ((lane >> 3) & 3)) * 8;
        pb[t] = (const char*)(WT + (size_t)brow * EDIM + scol);
    }

    auto STAGE = [&](int bufn, int ko) {
        char* abase = &Asraw[bufn][0] + w * (AFP32 ? 4096 : 2048);
        if constexpr (AFP32) {
#pragma unroll
            for (int t = 0; t < 4; ++t)
                glds16(pa[t] + (size_t)ko * 4, abase + t * 1024);
        } else {
#pragma unroll
            for (int t = 0; t < 2; ++t)
                glds16(pa[t] + (size_t)ko * 2, abase + t * 1024);
        }
        char* bbase = (char*)&Bs[bufn][0][0] + w * 2048;
#pragma unroll
        for (int t = 0; t < 2; ++t)
            glds16(pb[t] + (size_t)ko * 2, bbase + t * 1024);
    };

    f32x4 acc[4][4] = {};
    constexpr int NT = EDIM / 32;     // 32 K-steps

    STAGE(0, 0);
    STAGE(1, 32);
    if constexpr (AFP32) VMCNT(6); else VMCNT(4);   // tile0 landed
    __builtin_amdgcn_s_barrier();

    int bcur = 0, bn1 = 1, bn2 = 2;
#pragma unroll 1
    for (int kt = 0; kt < NT; ++kt) {
        if (kt + 2 < NT) STAGE(bn2, (kt + 2) * 32);

        bf16x8 af[4], bfr[4];
        if constexpr (AFP32) {
            const float* As = (const float*)&Asraw[bcur][0];
            const int x = l15 & 7;
#pragma unroll
            for (int i = 0; i < 4; ++i) {
                const int row = wrow * 64 + i * 16 + l15;
                f32x4 u0 = *(const f32x4*)(As + row * 32 + (((2 * g)     ^ x) * 4));
                f32x4 u1 = *(const f32x4*)(As + row * 32 + (((2 * g + 1) ^ x) * 4));
#pragma unroll
                for (int j = 0; j < 4; ++j) {
                    af[i][j]     = (__bf16)u0[j];
                    af[i][4 + j] = (__bf16)u1[j];
                }
            }
        } else {
            const u16* As = (const u16*)&Asraw[bcur][0];
            const int x = (l15 >> 1) & 3;
#pragma unroll
            for (int i = 0; i < 4; ++i) {
                const int row = wrow * 64 + i * 16 + l15;
                af[i] = bc(*(const us8*)(As + row * 32 + ((g ^ x) * 8)));
            }
        }
        {
            const int x = (l15 >> 1) & 3;
#pragma unroll
            for (int j = 0; j < 4; ++j) {
                const int row = wcol * 64 + j * 16 + l15;
                bfr[j] = bc(*(const us8*)((const u16*)&Bs[bcur][0][0] + row * 32 + ((g ^ x) * 8)));
            }
        }

#pragma unroll
        for (int i = 0; i < 4; ++i)
#pragma unroll
            for (int j = 0; j < 4; ++j)
                acc[i][j] = __builtin_amdgcn_mfma_f32_16x16x32_bf16(af[i], bfr[j], acc[i][j], 0, 0, 0);

        if (kt + 1 < NT) {
            if (kt + 2 < NT) {      // wait tile kt+1 only; kt+2 stays in flight
                if constexpr (AFP32) VMCNT(6); else VMCNT(4);
            } else {
                VMCNT(0);
            }
            __builtin_amdgcn_s_barrier();
        }
        const int t = bcur; bcur = bn1; bn1 = bn2; bn2 = t;
    }

    // epilogue: C/D layout: col = lane&15, row = (lane>>4)*4 + r
#pragma unroll
    for (int i = 0; i < 4; ++i) {
#pragma unroll
        for (int j = 0; j < 4; ++j) {
            const int gm0 = bm * 128 + wrow * 64 + i * 16 + g * 4;
            const int gn  = bn * 128 + wcol * 64 + j * 16 + l15;
            const float bv = bias[gn];
#pragma unroll
            for (int r = 0; r < 4; ++r) {
                float val = (acc[i][j][r] + bv) * oscale;
                const int m = gm0 + r;
                if constexpr (GATHER) {
                    if ((m & 2047) >= cn) val = 0.f;
                }
                if constexpr (MODE == 2) {
                    ((float*)outp)[(size_t)m * EDIM + gn] = val;
                } else {
                    const int b = m >> 11, s = m & 2047;
                    const int h = gn >> 6, d = gn & 63;
                    u16* O = (u16*)outp;
                    if constexpr (MODE == 0)
                        O[((size_t)(b * NHEAD + h) << 17) + s * HDIM + d] = bfbits(val);
                    else
                        O[((size_t)(b * NHEAD + h) << 17) + d * SEQ + s] = bfbits(val);
                }
            }
        }
    }
}

// ---------------------------------------------------------------------------
// Kernel 3: flash attention over COMPACTED keys, 32x32 MFMA, in-register P.
// ZERO LDS / ZERO barriers: K and V fragments read directly from global
// (L2-resident: 512KB KV per bh, 8 bh per XCD = 4MB). 4 independent waves
// per block. 1D grid 1024 blocks (XCD-mapped), 4 waves x 32 q-rows.
// K loads issued before V loads; compiler's FIFO vmcnt keeps V in flight
// during QK^T MFMAs.
// ---------------------------------------------------------------------------
__global__ __launch_bounds__(256) void attn_kernel(const u16* __restrict__ Q,
                                                   const u16* __restrict__ K,
                                                   const u16* __restrict__ VT,
                                                   const int* __restrict__ cntp,
                                                   u16* __restrict__ O) {
    const int tid = threadIdx.x, lane = tid & 63, w = tid >> 6;
    const int h = lane >> 5, l31 = lane & 31;

    const int id  = blockIdx.x;             // 0..1023, XCD-aware mapping
    const int bh  = (id & 7) * 8 + ((id >> 3) >> 4);
    const int qb  = (id >> 3) & 15;
    const int b   = bh >> 4, hd_ = bh & 15;

    const u16* Qp = Q + ((size_t)bh << 17);
    const u16* Kp = K + ((size_t)bh << 17);
    const u16* Vp = VT + ((size_t)bh << 17);
    const int q0w = qb * 128 + w * 32;

    const int cn  = cntp[b];
    const int ktc = (cn + 63) >> 6;

    // Q fragments (B-operand): B[k=16*khd+8h+j][col=q=l31]
    bf16x8 qf[4];
#pragma unroll
    for (int khd = 0; khd < 4; ++khd)
        qf[khd] = bc(*(const us8*)&Qp[(size_t)(q0w + l31) * HDIM + khd * 16 + h * 8]);

    // key permutation (C-regs == PV B-fragments)
    const int b_  = l31 & 3, hp = (l31 >> 2) & 1, cc = l31 >> 3;
    const int piR = 16 * (cc & 1) + 8 * hp + 4 * (cc >> 1) + b_;

    // per-lane global bases
    const u16* Kl = Kp + piR * HDIM + h * 8;            // K row piR, hd-chunk h
    const u16* Vl = Vp + (size_t)l31 * SEQ + h * 8;     // V^T row l31, key-chunk h

    f32x16 ot[2] = {};
    f32x16 ls = {};                         // row-sum acc (all regs identical)

    bf16x8 onesf;
#pragma unroll
    for (int j = 0; j < 8; ++j) onesf[j] = (__bf16)1.0f;

    for (int kt = 0; kt < ktc; ++kt) {
        const int kb = kt * 64;

        // K fragment loads first (QK^T waits only on these)
        us8 kr[2][4];
#pragma unroll
        for (int kb2 = 0; kb2 < 2; ++kb2)
#pragma unroll
            for (int khd = 0; khd < 4; ++khd)
                kr[kb2][khd] = *(const us8*)(Kl + (size_t)(kb + kb2 * 32) * HDIM + khd * 16);
        // V fragment loads (stay in flight during QK^T)
        us8 vr[2][4];
#pragma unroll
        for (int dblk = 0; dblk < 2; ++dblk)
#pragma unroll
            for (int s = 0; s < 4; ++s)
                vr[dblk][s] = *(const us8*)(Vl + (size_t)dblk * 32 * SEQ + kb + s * 16);

        // QK^T (key-permuted A rows); K already carries the softmax scale
        f32x16 st[2] = {};
        __builtin_amdgcn_s_setprio(1);
#pragma unroll
        for (int kb2 = 0; kb2 < 2; ++kb2)
#pragma unroll
            for (int khd = 0; khd < 4; ++khd)
                st[kb2] = __builtin_amdgcn_mfma_f32_32x32x16_bf16(bc(kr[kb2][khd]), qf[khd], st[kb2], 0, 0, 0);
        __builtin_amdgcn_s_setprio(0);

        // p = 2^st, in place
#pragma unroll
        for (int kb2 = 0; kb2 < 2; ++kb2)
#pragma unroll
            for (int e = 0; e < 16; ++e)
                st[kb2][e] = exp2fast(st[kb2][e]);

        // tail tile: zero the padded keys (>= cn)
        if (kt == ktc - 1) {
#pragma unroll
            for (int kb2 = 0; kb2 < 2; ++kb2)
#pragma unroll
                for (int cp = 0; cp < 4; ++cp)
#pragma unroll
                    for (int j = 0; j < 4; ++j) {
                        const int key = kb + kb2 * 32 + 16 * (cp & 1) + 4 * (cp >> 1) + 8 * h + j;
                        if (key >= cn) st[kb2][cp * 4 + j] = 0.f;
                    }
        }

        // PV B-fragments straight from registers
        bf16x8 pf[4];
#pragma unroll
        for (int s = 0; s < 4; ++s) {
            const int kb2 = s >> 1, sel = (s & 1) * 4;
#pragma unroll
            for (int j = 0; j < 4; ++j) {
                pf[s][j]     = (__bf16)st[kb2][sel + j];
                pf[s][4 + j] = (__bf16)st[kb2][8 + sel + j];
            }
        }

        __builtin_amdgcn_s_setprio(1);
        // row-sum: ls += ones * P (sums this tile's 64 keys per q-column)
#pragma unroll
        for (int s = 0; s < 4; ++s)
            ls = __builtin_amdgcn_mfma_f32_32x32x16_bf16(onesf, pf[s], ls, 0, 0, 0);
        // PV: A = V^T rows (d), B = P
#pragma unroll
        for (int dblk = 0; dblk < 2; ++dblk)
#pragma unroll
            for (int s = 0; s < 4; ++s)
                ot[dblk] = __builtin_amdgcn_mfma_f32_32x32x16_bf16(bc(vr[dblk][s]), pf[s], ot[dblk], 0, 0, 0);
        __builtin_amdgcn_s_setprio(0);
    }

    const float inv = 1.f / ls[0];          // all ls regs equal: full key sum

    // store: lane (h,l31) q=l31, d = dblk*32 + 8*cp + 4h + j
    const size_t row = (size_t)(b * SEQ + q0w + l31) * EDIM + hd_ * HDIM;
#pragma unroll
    for (int dblk = 0; dblk < 2; ++dblk) {
#pragma unroll
        for (int cp = 0; cp < 4; ++cp) {
            bf16x4 t;
#pragma unroll
            for (int j = 0; j < 4; ++j)
                t[j] = (__bf16)(ot[dblk][cp * 4 + j] * inv);
            *(bf16x4*)&O[row + dblk * 32 + 8 * cp + 4 * h] = t;
        }
    }
}

// ---------------------------------------------------------------------------
extern "C" void kernel_launch(void* const* d_in, const int* in_sizes, int n_in,
                              void* d_out, int out_size, void* d_ws, size_t ws_size,
                              hipStream_t stream) {
    const float* query = (const float*)d_in[0];
    const float* key   = (const float*)d_in[1];
    const float* value = (const float*)d_in[2];
    const int*   mask  = (const int*)d_in[3];
    const float* Wq = (const float*)d_in[4];  const float* bq = (const float*)d_in[5];
    const float* Wk = (const float*)d_in[6];  const float* bk = (const float*)d_in[7];
    const float* Wv = (const float*)d_in[8];  const float* bv = (const float*)d_in[9];
    const float* Wo = (const float*)d_in[10]; const float* bo = (const float*)d_in[11];

    char* ws = (char*)d_ws;
    const size_t WT_BYTES  = (size_t)EDIM * EDIM * 2;
    const size_t BUF_BYTES = (size_t)MTOK * EDIM * 2;
    u16* wtq   = (u16*)(ws);
    u16* wtk   = (u16*)(ws + WT_BYTES);
    u16* wtv   = (u16*)(ws + 2 * WT_BYTES);
    u16* wto   = (u16*)(ws + 3 * WT_BYTES);
    u16* Qbuf  = (u16*)(ws + 4 * WT_BYTES);
    u16* Kbuf  = (u16*)(ws + 4 * WT_BYTES + BUF_BYTES);
    u16* VTbuf = (u16*)(ws + 4 * WT_BYTES + 2 * BUF_BYTES);
    u16* Abuf  = (u16*)(ws + 4 * WT_BYTES + 3 * BUF_BYTES);
    int* idxl  = (int*)(ws + 4 * WT_BYTES + 4 * BUF_BYTES);
    int* cntp  = (int*)(ws + 4 * WT_BYTES + 4 * BUF_BYTES + (size_t)MTOK * 4);

    prep_kernel<<<NBAT, 256, 0, stream>>>(mask, idxl, cntp);

    dim3 tgrid(32, 32, 4), tblk(32, 8);
    wtrans4_kernel<<<tgrid, tblk, 0, stream>>>(Wq, Wk, Wv, Wo, wtq);

    gemm_kernel<0, true,  false><<<512, 256, 0, stream>>>(query, wtq, bq, Qbuf, nullptr, nullptr, 1.0f);
    gemm_kernel<0, true,  true ><<<512, 256, 0, stream>>>(key,   wtk, bk, Kbuf, idxl, cntp, SCL);
    gemm_kernel<1, true,  true ><<<512, 256, 0, stream>>>(value, wtv, bv, VTbuf, idxl, cntp, 1.0f);

    attn_kernel<<<1024, 256, 0, stream>>>(Qbuf, Kbuf, VTbuf, cntp, Abuf);

    gemm_kernel<2, false, false><<<512, 256, 0, stream>>>(Abuf, wto, bo, (float*)d_out, nullptr, nullptr, 1.0f);
}

// Round 9
// 179.650 us; speedup vs baseline: 1.5033x; 1.5033x over previous
//
#include <hip/hip_runtime.h>

// MHA forward: out = softmax(mask(QK^T/8)) V, with QKV/out projections.
// B=4, S=2048, D=1024, H=16, hd=64. fp32 in/out, bf16 MFMA compute.
// Mask [B,1,1,S] -> compact K/V to unmasked keys (~50%). Softmax scale
// folded into K projection. Attn: LDS-staged K/V, conflict-free swizzles.

#define SEQ   2048
#define EDIM  1024
#define NHEAD 16
#define HDIM  64
#define NBAT  4
#define MTOK  8192           // B*S

typedef __attribute__((ext_vector_type(8))) __bf16 bf16x8;
typedef __attribute__((ext_vector_type(4))) __bf16 bf16x4;
typedef __attribute__((ext_vector_type(4))) float f32x4;
typedef __attribute__((ext_vector_type(16))) float f32x16;
typedef __attribute__((ext_vector_type(8))) unsigned short us8;
typedef unsigned short u16;

// log2(e)/8 : folds the 1/sqrt(hd) scale and the exp->exp2 conversion
#define SCL   0.1803368801111244f

__device__ __forceinline__ u16 bfbits(float f) {
    __bf16 h = (__bf16)f;
    return __builtin_bit_cast(u16, h);
}
__device__ __forceinline__ bf16x8 bc(us8 v) { return __builtin_bit_cast(bf16x8, v); }
__device__ __forceinline__ float exp2fast(float x) {
    float r;
    asm("v_exp_f32 %0, %1" : "=v"(r) : "v"(x));
    return r;
}
// async global->LDS, 16B per lane; LDS dest = wave-uniform base + lane*16
__device__ __forceinline__ void glds16(const void* g, void* l) {
    __builtin_amdgcn_global_load_lds(
        (const __attribute__((address_space(1))) unsigned int*)g,
        (__attribute__((address_space(3))) unsigned int*)l, 16, 0, 0);
}

// ---------------------------------------------------------------------------
// Kernel 0: per-batch compaction of the key mask.
// ---------------------------------------------------------------------------
__global__ __launch_bounds__(256) void prep_kernel(const int* __restrict__ mask,
                                                   int* __restrict__ idxl,
                                                   int* __restrict__ cntp) {
    __shared__ int psum[257];
    const int b = blockIdx.x, t = threadIdx.x;
    const int* mp = mask + b * SEQ;
    int m8[8]; int s = 0;
#pragma unroll
    for (int i = 0; i < 8; ++i) { m8[i] = mp[t * 8 + i]; s += (m8[i] != 0); }
    psum[t + 1] = s;
    __syncthreads();
    if (t == 0) { psum[0] = 0; for (int i = 1; i <= 256; ++i) psum[i] += psum[i - 1]; }
    __syncthreads();
    int ex = psum[t];
#pragma unroll
    for (int i = 0; i < 8; ++i)
        if (m8[i] != 0) idxl[b * SEQ + (ex++)] = t * 8 + i;
    if (t == 0) cntp[b] = psum[256];
}

// ---------------------------------------------------------------------------
// Kernel 1: 4x W [K,N] fp32 -> WT [N,K] bf16 (transpose + cast)
// ---------------------------------------------------------------------------
__global__ __launch_bounds__(256) void wtrans4_kernel(const float* __restrict__ W0,
                                                      const float* __restrict__ W1,
                                                      const float* __restrict__ W2,
                                                      const float* __restrict__ W3,
                                                      u16* __restrict__ WT) {
    __shared__ float tile[32][33];
    const int tx = threadIdx.x, ty = threadIdx.y;
    const int bx = blockIdx.x,  by = blockIdx.y, wz = blockIdx.z;
    const float* W = (wz == 0) ? W0 : (wz == 1) ? W1 : (wz == 2) ? W2 : W3;
    u16* O = WT + (size_t)wz * EDIM * EDIM;
#pragma unroll
    for (int i = 0; i < 4; ++i)
        tile[ty + i * 8][tx] = W[(size_t)(by * 32 + ty + i * 8) * EDIM + bx * 32 + tx];
    __syncthreads();
#pragma unroll
    for (int i = 0; i < 4; ++i) {
        int n = bx * 32 + ty + i * 8;
        int k = by * 32 + tx;
        O[(size_t)n * EDIM + k] = bfbits(tile[tx][ty + i * 8]);
    }
}

// ---------------------------------------------------------------------------
// Kernel 2a: merged QKV projections, one 1536-block launch.
//   which = id>>9: 0=Q (no gather, [B,H,S,64]), 1=K (gather, scaled, same),
//                  2=V (gather, [B,H,64,S] transposed).
// fp32 A staged via glds16 (swizzled source cols), 2-buffer, 1 barrier/step.
// XCD-resident A-panel mapping on sub = id&511.
// ---------------------------------------------------------------------------
__global__ __launch_bounds__(256) void qkv_gemm_kernel(
        const float* __restrict__ Aq, const float* __restrict__ Ak,
        const float* __restrict__ Av, const u16* __restrict__ WTall,
        const float* __restrict__ bqp, const float* __restrict__ bkp,
        const float* __restrict__ bvp,
        u16* __restrict__ Qb, u16* __restrict__ Kb, u16* __restrict__ Vb,
        const int* __restrict__ idxl, const int* __restrict__ cntp) {
    const int id    = blockIdx.x;
    const int which = id >> 9;            // 0,1,2
    const int sub   = id & 511;
    const int r_    = sub >> 3;
    const int grp   = r_ >> 5, bnq = (r_ >> 2) & 7, bmin = r_ & 3;
    const int bm    = (sub & 7) + 8 * (grp * 4 + bmin);
    const int bn    = bnq;

    const float* A    = (which == 0) ? Aq : (which == 1) ? Ak : Av;
    const u16*   WT   = WTall + (size_t)which * EDIM * EDIM;
    const float* bias = (which == 0) ? bqp : (which == 1) ? bkp : bvp;
    u16*         outp = (which == 0) ? Qb : (which == 1) ? Kb : Vb;
    const float  oscale = (which == 1) ? SCL : 1.0f;
    const bool   gather = (which > 0);

    int cn = SEQ;
    if (gather) {
        cn = cntp[bm >> 4];
        if (((bm & 15) * 128) >= cn) return;
    }

    __shared__ __align__(16) float As[2][128 * 32];
    __shared__ __align__(16) u16   Bs[2][128][32];

    const int tid  = threadIdx.x;
    const int lane = tid & 63, w = tid >> 6;
    const int g    = lane >> 4, l15 = lane & 15;
    const int wrow = w >> 1, wcol = w & 1;

    const char* pa[4];
#pragma unroll
    for (int t = 0; t < 4; ++t) {
        const int rloc = w * 32 + t * 8 + (lane >> 3);
        int arow;
        if (gather) {
            const int sloc = (bm & 15) * 128 + rloc;
            const int gi = (sloc < cn) ? idxl[(bm >> 4) * SEQ + sloc] : 0;
            arow = (bm >> 4) * SEQ + gi;
        } else arow = bm * 128 + rloc;
        const int scol = ((lane & 7) ^ (lane >> 3)) * 4;     // fp32 slot xor
        pa[t] = (const char*)(A + (size_t)arow * EDIM + scol);
    }
    const char* pb[2];
#pragma unroll
    for (int t = 0; t < 2; ++t) {
        const int rloc = w * 32 + t * 16 + (lane >> 2);
        const int brow = bn * 128 + rloc;
        const int scol = ((lane & 3) ^ ((lane >> 3) & 3)) * 8;
        pb[t] = (const char*)(WT + (size_t)brow * EDIM + scol);
    }

    auto STAGE = [&](int bufn, int ko) {
        char* abase = (char*)&As[bufn][0] + w * 4096;
#pragma unroll
        for (int t = 0; t < 4; ++t)
            glds16(pa[t] + (size_t)ko * 4, abase + t * 1024);
        char* bbase = (char*)&Bs[bufn][0][0] + w * 2048;
#pragma unroll
        for (int t = 0; t < 2; ++t)
            glds16(pb[t] + (size_t)ko * 2, bbase + t * 1024);
    };

    f32x4 acc[4][4] = {};
    constexpr int NT = EDIM / 32;

    STAGE(0, 0);
    __syncthreads();

    int buf = 0;
#pragma unroll 1
    for (int kt = 0; kt < NT; ++kt) {
        if (kt < NT - 1) STAGE(buf ^ 1, (kt + 1) * 32);

        bf16x8 af[4], bfr[4];
        {
            const float* Ab = &As[buf][0];
            const int x = l15 & 7;
#pragma unroll
            for (int i = 0; i < 4; ++i) {
                const int row = wrow * 64 + i * 16 + l15;
                f32x4 u0 = *(const f32x4*)(Ab + row * 32 + (((2 * g)     ^ x) * 4));
                f32x4 u1 = *(const f32x4*)(Ab + row * 32 + (((2 * g + 1) ^ x) * 4));
#pragma unroll
                for (int j = 0; j < 4; ++j) {
                    af[i][j]     = (__bf16)u0[j];
                    af[i][4 + j] = (__bf16)u1[j];
                }
            }
        }
        {
            const int x = (l15 >> 1) & 3;
#pragma unroll
            for (int j = 0; j < 4; ++j) {
                const int row = wcol * 64 + j * 16 + l15;
                bfr[j] = bc(*(const us8*)((const u16*)&Bs[buf][0][0] + row * 32 + ((g ^ x) * 8)));
            }
        }

#pragma unroll
        for (int i = 0; i < 4; ++i)
#pragma unroll
            for (int j = 0; j < 4; ++j)
                acc[i][j] = __builtin_amdgcn_mfma_f32_16x16x32_bf16(af[i], bfr[j], acc[i][j], 0, 0, 0);

        __syncthreads();
        buf ^= 1;
    }

    // epilogue: C/D layout: col = lane&15, row = (lane>>4)*4 + r
#pragma unroll
    for (int i = 0; i < 4; ++i) {
#pragma unroll
        for (int j = 0; j < 4; ++j) {
            const int gm0 = bm * 128 + wrow * 64 + i * 16 + g * 4;
            const int gn  = bn * 128 + wcol * 64 + j * 16 + l15;
            const float bv = bias[gn];
#pragma unroll
            for (int r = 0; r < 4; ++r) {
                float val = (acc[i][j][r] + bv) * oscale;
                const int m = gm0 + r;
                if (gather && (m & 2047) >= cn) val = 0.f;
                const int b = m >> 11, s = m & 2047;
                const int h = gn >> 6, d = gn & 63;
                if (which == 2)
                    outp[((size_t)(b * NHEAD + h) << 17) + d * SEQ + s] = bfbits(val);
                else
                    outp[((size_t)(b * NHEAD + h) << 17) + s * HDIM + d] = bfbits(val);
            }
        }
    }
}

// ---------------------------------------------------------------------------
// Kernel 2b: O-projection. C[M,N] fp32 = Abuf(bf16)[M,1024] * Wo + bo.
// ---------------------------------------------------------------------------
__global__ __launch_bounds__(256) void o_gemm_kernel(const u16* __restrict__ Ap,
                                                     const u16* __restrict__ WT,
                                                     const float* __restrict__ bias,
                                                     float* __restrict__ outp) {
    const int id  = blockIdx.x;
    const int r_  = id >> 3;
    const int grp = r_ >> 5, bnq = (r_ >> 2) & 7, bmin = r_ & 3;
    const int bm  = (id & 7) + 8 * (grp * 4 + bmin);
    const int bn  = bnq;

    __shared__ __align__(16) u16 As[2][128][32];
    __shared__ __align__(16) u16 Bs[2][128][32];

    const int tid  = threadIdx.x;
    const int lane = tid & 63, w = tid >> 6;
    const int g    = lane >> 4, l15 = lane & 15;
    const int wrow = w >> 1, wcol = w & 1;

    const char* pa[2]; const char* pb[2];
#pragma unroll
    for (int t = 0; t < 2; ++t) {
        const int rloc = w * 32 + t * 16 + (lane >> 2);
        const int scol = ((lane & 3) ^ ((lane >> 3) & 3)) * 8;
        pa[t] = (const char*)(Ap + (size_t)(bm * 128 + rloc) * EDIM + scol);
        pb[t] = (const char*)(WT + (size_t)(bn * 128 + rloc) * EDIM + scol);
    }

    auto STAGE = [&](int bufn, int ko) {
        char* abase = (char*)&As[bufn][0][0] + w * 2048;
        char* bbase = (char*)&Bs[bufn][0][0] + w * 2048;
#pragma unroll
        for (int t = 0; t < 2; ++t) {
            glds16(pa[t] + (size_t)ko * 2, abase + t * 1024);
            glds16(pb[t] + (size_t)ko * 2, bbase + t * 1024);
        }
    };

    f32x4 acc[4][4] = {};
    constexpr int NT = EDIM / 32;

    STAGE(0, 0);
    __syncthreads();

    int buf = 0;
#pragma unroll 1
    for (int kt = 0; kt < NT; ++kt) {
        if (kt < NT - 1) STAGE(buf ^ 1, (kt + 1) * 32);

        bf16x8 af[4], bfr[4];
        const int x = (l15 >> 1) & 3;
#pragma unroll
        for (int i = 0; i < 4; ++i) {
            const int rowA = wrow * 64 + i * 16 + l15;
            af[i] = bc(*(const us8*)((const u16*)&As[buf][0][0] + rowA * 32 + ((g ^ x) * 8)));
            const int rowB = wcol * 64 + i * 16 + l15;
            bfr[i] = bc(*(const us8*)((const u16*)&Bs[buf][0][0] + rowB * 32 + ((g ^ x) * 8)));
        }

#pragma unroll
        for (int i = 0; i < 4; ++i)
#pragma unroll
            for (int j = 0; j < 4; ++j)
                acc[i][j] = __builtin_amdgcn_mfma_f32_16x16x32_bf16(af[i], bfr[j], acc[i][j], 0, 0, 0);

        __syncthreads();
        buf ^= 1;
    }

#pragma unroll
    for (int i = 0; i < 4; ++i) {
#pragma unroll
        for (int j = 0; j < 4; ++j) {
            const int gm0 = bm * 128 + wrow * 64 + i * 16 + g * 4;
            const int gn  = bn * 128 + wcol * 64 + j * 16 + l15;
            const float bv = bias[gn];
#pragma unroll
            for (int r = 0; r < 4; ++r)
                outp[(size_t)(gm0 + r) * EDIM + gn] = acc[i][j][r] + bv;
        }
    }
}

// ---------------------------------------------------------------------------
// Kernel 3: flash attention over COMPACTED keys, 32x32 MFMA, in-register P.
// 1D grid 1024 blocks (XCD-mapped), 256 threads = 4 waves x 32 q-rows.
// K pre-scaled by log2e/8 -> p = exp2(st); tail-pad keys zeroed last tile.
// Row-sum via ones-MFMA. K/V staged via glds16, 2-buffer, 1 barrier/tile.
// LDS swizzles (16B slots, involution sigma(r,s)=s^f(r)):
//   K: f(r) = (r&3) | (((r>>3)&1)<<2)  -- uniform 8 lanes/slot (bank floor)
//   V: f(r) = r&7                      -- uniform per octet
// ---------------------------------------------------------------------------
__global__ __launch_bounds__(256) void attn_kernel(const u16* __restrict__ Q,
                                                   const u16* __restrict__ K,
                                                   const u16* __restrict__ VT,
                                                   const int* __restrict__ cntp,
                                                   u16* __restrict__ O) {
    __shared__ u16 Klds[2][64][64];
    __shared__ u16 Vlds[2][64][64];

    const int tid = threadIdx.x, lane = tid & 63, w = tid >> 6;
    const int h = lane >> 5, l31 = lane & 31;

    const int id  = blockIdx.x;             // 0..1023, XCD-aware mapping
    const int bh  = (id & 7) * 8 + ((id >> 3) >> 4);
    const int qb  = (id >> 3) & 15;
    const int b   = bh >> 4, hd_ = bh & 15;

    const u16* Qp = Q + ((size_t)bh << 17);
    const u16* Kp = K + ((size_t)bh << 17);
    const u16* Vp = VT + ((size_t)bh << 17);
    const int q0w = qb * 128 + w * 32;

    const int cn  = cntp[b];
    const int ktc = (cn + 63) >> 6;

    // Q fragments (B-operand): B[k=16*khd+8h+j][col=q=l31]
    bf16x8 qf[4];
#pragma unroll
    for (int khd = 0; khd < 4; ++khd)
        qf[khd] = bc(*(const us8*)&Qp[(size_t)(q0w + l31) * HDIM + khd * 16 + h * 8]);

    // key permutation (C-regs == PV B-fragments) + read-side swizzles
    const int b_  = l31 & 3, hp = (l31 >> 2) & 1, cc = l31 >> 3;
    const int piR = 16 * (cc & 1) + 8 * hp + 4 * (cc >> 1) + b_;
    const int swk = b_ | (hp << 2);          // f(kb2*32+piR) = (r&3)|(((r>>3)&1)<<2)
    const int swv = l31 & 7;

    // staging source pointers (glds: dest = wave base + lane*16, linear)
    const int lr = lane >> 3, lg = lane & 7;
    const u16* pKs[2]; const u16* pVs[2];
#pragma unroll
    for (int t = 0; t < 2; ++t) {
        const int rloc = w * 16 + t * 8 + lr;                 // LDS row 0..63
        const int xk = (rloc & 3) | (((rloc >> 3) & 1) << 2);
        pKs[t] = Kp + (size_t)rloc * HDIM + ((lg ^ xk) << 3);
        const int xv = rloc & 7;
        pVs[t] = Vp + (size_t)rloc * SEQ + ((lg ^ xv) << 3);
    }

    auto STAGE = [&](int bufn, int kb) {
#pragma unroll
        for (int t = 0; t < 2; ++t) {
            glds16(pKs[t] + (size_t)kb * HDIM, &Klds[bufn][w * 16 + t * 8][0]);
            glds16(pVs[t] + kb,                &Vlds[bufn][w * 16 + t * 8][0]);
        }
    };

    f32x16 ot[2] = {};
    f32x16 ls = {};                         // row-sum acc (all regs identical)

    bf16x8 onesf;
#pragma unroll
    for (int j = 0; j < 8; ++j) onesf[j] = (__bf16)1.0f;

    STAGE(0, 0);
    __syncthreads();

    for (int kt = 0; kt < ktc; ++kt) {
        const int cur = kt & 1;
        const bool more = (kt + 1) < ktc;
        if (more) STAGE(cur ^ 1, (kt + 1) * 64);

        // QK^T (key-permuted A rows); K already carries the softmax scale
        f32x16 st[2] = {};
        __builtin_amdgcn_s_setprio(1);
#pragma unroll
        for (int kb2 = 0; kb2 < 2; ++kb2) {
            const u16* Kr = &Klds[cur][kb2 * 32 + piR][0];
#pragma unroll
            for (int khd = 0; khd < 4; ++khd) {
                bf16x8 kf = bc(*(const us8*)&Kr[(khd * 16 + h * 8) ^ (swk << 3)]);
                st[kb2] = __builtin_amdgcn_mfma_f32_32x32x16_bf16(kf, qf[khd], st[kb2], 0, 0, 0);
            }
        }
        __builtin_amdgcn_s_setprio(0);

        // p = 2^st, in place
#pragma unroll
        for (int kb2 = 0; kb2 < 2; ++kb2)
#pragma unroll
            for (int e = 0; e < 16; ++e)
                st[kb2][e] = exp2fast(st[kb2][e]);

        // tail tile: zero the padded keys (>= cn)
        if (kt == ktc - 1) {
            const int kbase = kt * 64;
#pragma unroll
            for (int kb2 = 0; kb2 < 2; ++kb2)
#pragma unroll
                for (int cp = 0; cp < 4; ++cp)
#pragma unroll
                    for (int j = 0; j < 4; ++j) {
                        const int key = kbase + kb2 * 32 + 16 * (cp & 1) + 4 * (cp >> 1) + 8 * h + j;
                        if (key >= cn) st[kb2][cp * 4 + j] = 0.f;
                    }
        }

        // PV B-fragments straight from registers
        bf16x8 pf[4];
#pragma unroll
        for (int s = 0; s < 4; ++s) {
            const int kb2 = s >> 1, sel = (s & 1) * 4;
#pragma unroll
            for (int j = 0; j < 4; ++j) {
                pf[s][j]     = (__bf16)st[kb2][sel + j];
                pf[s][4 + j] = (__bf16)st[kb2][8 + sel + j];
            }
        }

        __builtin_amdgcn_s_setprio(1);
        // row-sum: ls += ones * P (sums this tile's 64 keys per q-column)
#pragma unroll
        for (int s = 0; s < 4; ++s)
            ls = __builtin_amdgcn_mfma_f32_32x32x16_bf16(onesf, pf[s], ls, 0, 0, 0);
        // PV: A = V^T rows (d), B = P
#pragma unroll
        for (int dblk = 0; dblk < 2; ++dblk) {
            const u16* Vr = &Vlds[cur][dblk * 32 + l31][0];
#pragma unroll
            for (int s = 0; s < 4; ++s) {
                bf16x8 vf = bc(*(const us8*)&Vr[(s * 16 + h * 8) ^ (swv << 3)]);
                ot[dblk] = __builtin_amdgcn_mfma_f32_32x32x16_bf16(vf, pf[s], ot[dblk], 0, 0, 0);
            }
        }
        __builtin_amdgcn_s_setprio(0);

        __syncthreads();                    // drains glds (next buf ready)
    }

    const float inv = 1.f / ls[0];          // all ls regs equal: full key sum

    // store: lane (h,l31) q=l31, d = dblk*32 + 8*cp + 4h + j
    const size_t row = (size_t)(b * SEQ + q0w + l31) * EDIM + hd_ * HDIM;
#pragma unroll
    for (int dblk = 0; dblk < 2; ++dblk) {
#pragma unroll
        for (int cp = 0; cp < 4; ++cp) {
            bf16x4 t;
#pragma unroll
            for (int j = 0; j < 4; ++j)
                t[j] = (__bf16)(ot[dblk][cp * 4 + j] * inv);
            *(bf16x4*)&O[row + dblk * 32 + 8 * cp + 4 * h] = t;
        }
    }
}

// ---------------------------------------------------------------------------
extern "C" void kernel_launch(void* const* d_in, const int* in_sizes, int n_in,
                              void* d_out, int out_size, void* d_ws, size_t ws_size,
                              hipStream_t stream) {
    const float* query = (const float*)d_in[0];
    const float* key   = (const float*)d_in[1];
    const float* value = (const float*)d_in[2];
    const int*   mask  = (const int*)d_in[3];
    const float* Wq = (const float*)d_in[4];  const float* bq = (const float*)d_in[5];
    const float* Wk = (const float*)d_in[6];  const float* bk = (const float*)d_in[7];
    const float* Wv = (const float*)d_in[8];  const float* bv = (const float*)d_in[9];
    const float* Wo = (const float*)d_in[10]; const float* bo = (const float*)d_in[11];

    char* ws = (char*)d_ws;
    const size_t WT_BYTES  = (size_t)EDIM * EDIM * 2;
    const size_t BUF_BYTES = (size_t)MTOK * EDIM * 2;
    u16* wtq   = (u16*)(ws);                    // q,k,v,o contiguous
    u16* wto   = (u16*)(ws + 3 * WT_BYTES);
    u16* Qbuf  = (u16*)(ws + 4 * WT_BYTES);
    u16* Kbuf  = (u16*)(ws + 4 * WT_BYTES + BUF_BYTES);
    u16* VTbuf = (u16*)(ws + 4 * WT_BYTES + 2 * BUF_BYTES);
    u16* Abuf  = (u16*)(ws + 4 * WT_BYTES + 3 * BUF_BYTES);
    int* idxl  = (int*)(ws + 4 * WT_BYTES + 4 * BUF_BYTES);
    int* cntp  = (int*)(ws + 4 * WT_BYTES + 4 * BUF_BYTES + (size_t)MTOK * 4);

    prep_kernel<<<NBAT, 256, 0, stream>>>(mask, idxl, cntp);

    dim3 tgrid(32, 32, 4), tblk(32, 8);
    wtrans4_kernel<<<tgrid, tblk, 0, stream>>>(Wq, Wk, Wv, Wo, wtq);

    qkv_gemm_kernel<<<1536, 256, 0, stream>>>(query, key, value, wtq,
                                              bq, bk, bv, Qbuf, Kbuf, VTbuf,
                                              idxl, cntp);

    attn_kernel<<<1024, 256, 0, stream>>>(Qbuf, Kbuf, VTbuf, cntp, Abuf);

    o_gemm_kernel<<<512, 256, 0, stream>>>(Abuf, wto, bo, (float*)d_out);
}